// Round 2
// baseline (1070.816 us; speedup 1.0000x reference)
//
#include <hip/hip_runtime.h>
#include <cstdint>
#include <cmath>

// ---------------------------------------------------------------------------
// SimpleTransformerBlock on MI355X (gfx950)
// B=4, L=4096 -> 16384 tokens, D=1024, HEADS=16, HEAD_DIM=64
// All ops are token-parallel (attention mixes heads WITHIN a token), so the
// whole pipeline is chunked over token blocks sized to fit ws_size.
// bf16 MFMA (16x16x32) GEMMs, fp32 accumulation.
// ---------------------------------------------------------------------------

#define NTOK   16384
#define DMODEL 1024

typedef __bf16 bf16x8 __attribute__((ext_vector_type(8)));
typedef float  f32x4  __attribute__((ext_vector_type(4)));

__device__ __forceinline__ unsigned short f2bf(float f) {
    unsigned int u = __builtin_bit_cast(unsigned int, f);
    u += 0x7fffu + ((u >> 16) & 1u);          // round-to-nearest-even
    return (unsigned short)(u >> 16);
}
__device__ __forceinline__ float bf2f(unsigned short s) {
    unsigned int u = ((unsigned int)s) << 16;
    return __builtin_bit_cast(float, u);
}

// ---------------------------------------------------------------------------
// fp32 -> bf16 cast (weights)
// ---------------------------------------------------------------------------
__global__ __launch_bounds__(256) void cast_f32_bf16(
    const float4* __restrict__ in, ushort4* __restrict__ out, int n4) {
    int i = blockIdx.x * 256 + threadIdx.x;
    if (i < n4) {
        float4 v = in[i];
        ushort4 o;
        o.x = f2bf(v.x); o.y = f2bf(v.y); o.z = f2bf(v.z); o.w = f2bf(v.w);
        out[i] = o;
    }
}

// ---------------------------------------------------------------------------
// LayerNorm (fp32 in) -> bf16 out.  One block (256 thr) per token, D=1024.
// ---------------------------------------------------------------------------
__global__ __launch_bounds__(256) void ln_cast(
    const float* __restrict__ x, const float* __restrict__ w,
    const float* __restrict__ b, unsigned short* __restrict__ out) {
    int tok = blockIdx.x;
    int t   = threadIdx.x;
    float4 v = ((const float4*)x)[tok * 256 + t];
    float s  = v.x + v.y + v.z + v.w;
    float ss = v.x * v.x + v.y * v.y + v.z * v.z + v.w * v.w;
    #pragma unroll
    for (int off = 32; off > 0; off >>= 1) {
        s  += __shfl_down(s, off);
        ss += __shfl_down(ss, off);
    }
    __shared__ float red[8];
    int wave = t >> 6;
    if ((t & 63) == 0) { red[wave * 2] = s; red[wave * 2 + 1] = ss; }
    __syncthreads();
    s  = red[0] + red[2] + red[4] + red[6];
    ss = red[1] + red[3] + red[5] + red[7];
    float mu  = s * (1.0f / 1024.0f);
    float var = ss * (1.0f / 1024.0f) - mu * mu;
    float rs  = rsqrtf(var + 1e-5f);
    float4 wv = ((const float4*)w)[t];
    float4 bv = ((const float4*)b)[t];
    ushort4 o;
    o.x = f2bf((v.x - mu) * rs * wv.x + bv.x);
    o.y = f2bf((v.y - mu) * rs * wv.y + bv.y);
    o.z = f2bf((v.z - mu) * rs * wv.z + bv.z);
    o.w = f2bf((v.w - mu) * rs * wv.w + bv.w);
    ((ushort4*)out)[tok * 256 + t] = o;
}

// ---------------------------------------------------------------------------
// Per-token head-attention: qkv row [3][16][64] bf16 -> out row [16*64] bf16.
// One block (256 thr) per token.
// ---------------------------------------------------------------------------
__global__ __launch_bounds__(256) void attn_heads(
    const unsigned short* __restrict__ qkv, unsigned short* __restrict__ out) {
    __shared__ float sQ[1024], sK[1024], sV[1024];
    __shared__ float sS[256];
    int tok = blockIdx.x;
    int t   = threadIdx.x;
    const unsigned short* base = qkv + (size_t)tok * 3072;
    for (int i = t; i < 1024; i += 256) {
        sQ[i] = bf2f(base[i]);
        sK[i] = bf2f(base[1024 + i]);
        sV[i] = bf2f(base[2048 + i]);
    }
    __syncthreads();
    {
        int h = t >> 4, g = t & 15;
        float s = 0.0f;
        #pragma unroll
        for (int d = 0; d < 64; ++d) s += sQ[h * 64 + d] * sK[g * 64 + d];
        sS[h * 16 + g] = s * 0.125f;   // 1/sqrt(64)
    }
    __syncthreads();
    if (t < 16) {
        float mx = -1e30f;
        for (int g = 0; g < 16; ++g) mx = fmaxf(mx, sS[t * 16 + g]);
        float sum = 0.0f;
        for (int g = 0; g < 16; ++g) {
            float e = expf(sS[t * 16 + g] - mx);
            sS[t * 16 + g] = e;
            sum += e;
        }
        float inv = 1.0f / sum;
        for (int g = 0; g < 16; ++g) sS[t * 16 + g] *= inv;
    }
    __syncthreads();
    #pragma unroll
    for (int j = 0; j < 4; ++j) {
        int o = t + 256 * j;
        int h = o >> 6, d = o & 63;
        float s = 0.0f;
        #pragma unroll
        for (int g = 0; g < 16; ++g) s += sS[h * 16 + g] * sV[g * 64 + d];
        out[(size_t)tok * 1024 + o] = f2bf(s);
    }
}

// ---------------------------------------------------------------------------
// bf16 GEMM:  C[M,N] = A[M,K] . W[N,K]^T  (+ bias, + epilogue)
//   EPI 0: out bf16 = acc + bias                      (QKV)
//   EPI 1: out f32  = acc + bias + resid              (proj / MLP2; resid may
//                                                      alias Cout)
//   EPI 2: out bf16 = gelu_exact(acc + bias)          (MLP1)
// 128x128 tile, BK=32, 4 waves in 2x2, each wave 64x64 via 4x4
// mfma_f32_16x16x32_bf16.  LDS stride 40 shorts (80 B): conflict-safe,
// 16B-aligned for ds_read_b128.  Layouts per verified m89/m91/m92 mappings.
// ---------------------------------------------------------------------------
#define BM 128
#define BN 128
#define BK 32
#define LDST 40

template <int EPI>
__global__ __launch_bounds__(256) void gemm_bf16(
    const unsigned short* __restrict__ A, const unsigned short* __restrict__ W,
    const float* __restrict__ bias, const float* resid, void* Cout,
    int M, int N, int K) {
    __shared__ __align__(16) unsigned short As[BM * LDST];
    __shared__ __align__(16) unsigned short Bs[BN * LDST];

    const int t    = threadIdx.x;
    const int lane = t & 63;
    const int wave = t >> 6;
    const int wm   = wave >> 1;
    const int wn   = wave & 1;
    const int m0   = blockIdx.y * BM;
    const int n0   = blockIdx.x * BN;

    const int rowA0 = t >> 2,          colA0 = (t & 3) * 8;
    const int rowA1 = (t + 256) >> 2,  colA1 = colA0;

    const int fr = lane & 15;   // fragment row (m or n within 16)
    const int fq = lane >> 4;   // quad -> k offset = fq*8

    f32x4 acc[4][4] = {};

    for (int k0 = 0; k0 < K; k0 += BK) {
        uint4 a0 = *(const uint4*)(A + (size_t)(m0 + rowA0) * K + k0 + colA0);
        uint4 a1 = *(const uint4*)(A + (size_t)(m0 + rowA1) * K + k0 + colA1);
        uint4 b0 = *(const uint4*)(W + (size_t)(n0 + rowA0) * K + k0 + colA0);
        uint4 b1 = *(const uint4*)(W + (size_t)(n0 + rowA1) * K + k0 + colA1);
        __syncthreads();   // all waves done reading LDS from previous iter
        *(uint4*)(As + rowA0 * LDST + colA0) = a0;
        *(uint4*)(As + rowA1 * LDST + colA1) = a1;
        *(uint4*)(Bs + rowA0 * LDST + colA0) = b0;
        *(uint4*)(Bs + rowA1 * LDST + colA1) = b1;
        __syncthreads();

        bf16x8 af[4], bf[4];
        #pragma unroll
        for (int i = 0; i < 4; ++i)
            af[i] = *(const bf16x8*)(As + (wm * 64 + i * 16 + fr) * LDST + fq * 8);
        #pragma unroll
        for (int i = 0; i < 4; ++i)
            bf[i] = *(const bf16x8*)(Bs + (wn * 64 + i * 16 + fr) * LDST + fq * 8);
        #pragma unroll
        for (int im = 0; im < 4; ++im)
            #pragma unroll
            for (int in = 0; in < 4; ++in)
                acc[im][in] = __builtin_amdgcn_mfma_f32_16x16x32_bf16(
                    af[im], bf[in], acc[im][in], 0, 0, 0);
    }

    // epilogue: C/D layout col = lane&15, row = (lane>>4)*4 + e
    #pragma unroll
    for (int in = 0; in < 4; ++in) {
        int col = n0 + wn * 64 + in * 16 + fr;
        float bv = bias[col];
        #pragma unroll
        for (int im = 0; im < 4; ++im) {
            int rowb = m0 + wm * 64 + im * 16 + fq * 4;
            #pragma unroll
            for (int e = 0; e < 4; ++e) {
                size_t idx = (size_t)(rowb + e) * N + col;
                float v = acc[im][in][e] + bv;
                if (EPI == 0) {
                    ((unsigned short*)Cout)[idx] = f2bf(v);
                } else if (EPI == 1) {
                    ((float*)Cout)[idx] = v + resid[idx];
                } else {
                    float g = 0.5f * v * (1.0f + erff(v * 0.70710678118654752f));
                    ((unsigned short*)Cout)[idx] = f2bf(g);
                }
            }
        }
    }
}

// ---------------------------------------------------------------------------
// launch — chunked over token blocks sized to fit ws_size.
// ---------------------------------------------------------------------------
extern "C" void kernel_launch(void* const* d_in, const int* in_sizes, int n_in,
                              void* d_out, int out_size, void* d_ws, size_t ws_size,
                              hipStream_t stream) {
    const float* x      = (const float*)d_in[0];
    const float* qkv_w  = (const float*)d_in[1];
    const float* qkv_b  = (const float*)d_in[2];
    const float* proj_w = (const float*)d_in[3];
    const float* proj_b = (const float*)d_in[4];
    const float* ln1_w  = (const float*)d_in[5];
    const float* ln1_b  = (const float*)d_in[6];
    const float* ln2_w  = (const float*)d_in[7];
    const float* ln2_b  = (const float*)d_in[8];
    const float* mlp_w1 = (const float*)d_in[9];
    const float* mlp_b1 = (const float*)d_in[10];
    const float* mlp_w2 = (const float*)d_in[11];
    const float* mlp_b2 = (const float*)d_in[12];
    float* out = (float*)d_out;

    // persistent bf16 weights: 24 MB
    const size_t WB = 25165824;
    char* ws = (char*)d_ws;
    unsigned short* w_qkv  = (unsigned short*)(ws);              // [3072,1024]
    unsigned short* w_proj = (unsigned short*)(ws + 6291456);    // [1024,1024]
    unsigned short* w_m1   = (unsigned short*)(ws + 8388608);    // [4096,1024]
    unsigned short* w_m2   = (unsigned short*)(ws + 16777216);   // [1024,4096]

    // pick largest chunk T (tokens) fitting:  WB + T*(2048 h + 2048 attn + 8192 qkv|m)
    int T = NTOK;
    while (T >= 256 && WB + (size_t)T * 12288 > ws_size) T >>= 1;
    if (T < 256) {
        // ws too small for this design — graceful numeric failure, not a crash
        hipMemcpyAsync(out, x, (size_t)NTOK * DMODEL * sizeof(float),
                       hipMemcpyDeviceToDevice, stream);
        return;
    }

    unsigned short* hbuf = (unsigned short*)(ws + WB);                     // T*2048 B (h, then h2)
    unsigned short* abuf = (unsigned short*)(ws + WB + (size_t)T * 2048);  // T*2048 B (attn out)
    unsigned short* qmbuf= (unsigned short*)(ws + WB + (size_t)T * 4096);  // T*8192 B (qkv, then mlp hidden)

    // weight casts fp32 -> bf16 (once per call)
    cast_f32_bf16<<<3072, 256, 0, stream>>>((const float4*)qkv_w,  (ushort4*)w_qkv,  786432);
    cast_f32_bf16<<<1024, 256, 0, stream>>>((const float4*)proj_w, (ushort4*)w_proj, 262144);
    cast_f32_bf16<<<4096, 256, 0, stream>>>((const float4*)mlp_w1, (ushort4*)w_m1,   1048576);
    cast_f32_bf16<<<4096, 256, 0, stream>>>((const float4*)mlp_w2, (ushort4*)w_m2,   1048576);

    for (int tok0 = 0; tok0 < NTOK; tok0 += T) {
        const float* xc   = x   + (size_t)tok0 * DMODEL;
        float*       outc = out + (size_t)tok0 * DMODEL;

        // h = LN1(x)
        ln_cast<<<T, 256, 0, stream>>>(xc, ln1_w, ln1_b, hbuf);
        // qkv = h @ qkv_w.T + qkv_b
        gemm_bf16<0><<<dim3(3072 / BN, T / BM), 256, 0, stream>>>(
            hbuf, w_qkv, qkv_b, nullptr, qmbuf, T, 3072, 1024);
        // per-token head attention
        attn_heads<<<T, 256, 0, stream>>>(qmbuf, abuf);
        // x1 = x + attn @ proj_w.T + proj_b   (fp32, into d_out rows)
        gemm_bf16<1><<<dim3(1024 / BN, T / BM), 256, 0, stream>>>(
            abuf, w_proj, proj_b, xc, (void*)outc, T, 1024, 1024);
        // h2 = LN2(x1)  (reuse hbuf)
        ln_cast<<<T, 256, 0, stream>>>(outc, ln2_w, ln2_b, hbuf);
        // m = gelu(h2 @ mlp_w1.T + mlp_b1)   (reuse qmbuf)
        gemm_bf16<2><<<dim3(4096 / BN, T / BM), 256, 0, stream>>>(
            hbuf, w_m1, mlp_b1, nullptr, qmbuf, T, 4096, 1024);
        // out = x1 + m @ mlp_w2.T + mlp_b2   (in-place residual on d_out rows)
        gemm_bf16<1><<<dim3(1024 / BN, T / BM), 256, 0, stream>>>(
            qmbuf, w_m2, mlp_b2, outc, (void*)outc, T, 1024, 4096);
    }
}

// Round 3
// 1049.601 us; speedup vs baseline: 1.0202x; 1.0202x over previous
//
#include <hip/hip_runtime.h>
#include <cstdint>
#include <cmath>

// ---------------------------------------------------------------------------
// SimpleTransformerBlock on MI355X (gfx950)
// B=4, L=4096 -> 16384 tokens, D=1024, HEADS=16, HEAD_DIM=64
// Round 2: m97-style GEMM — global_load_lds width-16 staging, XOR-swizzled
// LDS (conflict-free reads), XCD-sliced tile mapping for L2 locality.
// ---------------------------------------------------------------------------

#define NTOK   16384
#define DMODEL 1024

typedef __bf16 bf16x8 __attribute__((ext_vector_type(8)));
typedef float  f32x4  __attribute__((ext_vector_type(4)));
typedef unsigned int __attribute__((address_space(1))) as1_uint;
typedef unsigned int __attribute__((address_space(3))) as3_uint;

__device__ __forceinline__ unsigned short f2bf(float f) {
    unsigned int u = __builtin_bit_cast(unsigned int, f);
    u += 0x7fffu + ((u >> 16) & 1u);          // round-to-nearest-even
    return (unsigned short)(u >> 16);
}
__device__ __forceinline__ float bf2f(unsigned short s) {
    unsigned int u = ((unsigned int)s) << 16;
    return __builtin_bit_cast(float, u);
}

// async global->LDS, 16 B per lane; l must be wave-uniform (HW adds lane*16)
__device__ __forceinline__ void g2l16(const unsigned short* g, unsigned short* l) {
    __builtin_amdgcn_global_load_lds((const as1_uint*)g, (as3_uint*)l, 16, 0, 0);
}

// ---------------------------------------------------------------------------
// fp32 -> bf16 cast (weights)
// ---------------------------------------------------------------------------
__global__ __launch_bounds__(256) void cast_f32_bf16(
    const float4* __restrict__ in, ushort4* __restrict__ out, int n4) {
    int i = blockIdx.x * 256 + threadIdx.x;
    if (i < n4) {
        float4 v = in[i];
        ushort4 o;
        o.x = f2bf(v.x); o.y = f2bf(v.y); o.z = f2bf(v.z); o.w = f2bf(v.w);
        out[i] = o;
    }
}

// ---------------------------------------------------------------------------
// LayerNorm (fp32 in) -> bf16 out.  One block (256 thr) per token, D=1024.
// ---------------------------------------------------------------------------
__global__ __launch_bounds__(256) void ln_cast(
    const float* __restrict__ x, const float* __restrict__ w,
    const float* __restrict__ b, unsigned short* __restrict__ out) {
    int tok = blockIdx.x;
    int t   = threadIdx.x;
    float4 v = ((const float4*)x)[tok * 256 + t];
    float s  = v.x + v.y + v.z + v.w;
    float ss = v.x * v.x + v.y * v.y + v.z * v.z + v.w * v.w;
    #pragma unroll
    for (int off = 32; off > 0; off >>= 1) {
        s  += __shfl_down(s, off);
        ss += __shfl_down(ss, off);
    }
    __shared__ float red[8];
    int wave = t >> 6;
    if ((t & 63) == 0) { red[wave * 2] = s; red[wave * 2 + 1] = ss; }
    __syncthreads();
    s  = red[0] + red[2] + red[4] + red[6];
    ss = red[1] + red[3] + red[5] + red[7];
    float mu  = s * (1.0f / 1024.0f);
    float var = ss * (1.0f / 1024.0f) - mu * mu;
    float rs  = rsqrtf(var + 1e-5f);
    float4 wv = ((const float4*)w)[t];
    float4 bv = ((const float4*)b)[t];
    ushort4 o;
    o.x = f2bf((v.x - mu) * rs * wv.x + bv.x);
    o.y = f2bf((v.y - mu) * rs * wv.y + bv.y);
    o.z = f2bf((v.z - mu) * rs * wv.z + bv.z);
    o.w = f2bf((v.w - mu) * rs * wv.w + bv.w);
    ((ushort4*)out)[tok * 256 + t] = o;
}

// ---------------------------------------------------------------------------
// Per-token head-attention: qkv row [3][16][64] bf16 -> out row [16*64] bf16.
// ---------------------------------------------------------------------------
__global__ __launch_bounds__(256) void attn_heads(
    const unsigned short* __restrict__ qkv, unsigned short* __restrict__ out) {
    __shared__ float sQ[1024], sK[1024], sV[1024];
    __shared__ float sS[256];
    int tok = blockIdx.x;
    int t   = threadIdx.x;
    const unsigned short* base = qkv + (size_t)tok * 3072;
    for (int i = t; i < 1024; i += 256) {
        sQ[i] = bf2f(base[i]);
        sK[i] = bf2f(base[1024 + i]);
        sV[i] = bf2f(base[2048 + i]);
    }
    __syncthreads();
    {
        int h = t >> 4, g = t & 15;
        float s = 0.0f;
        #pragma unroll
        for (int d = 0; d < 64; ++d) s += sQ[h * 64 + d] * sK[g * 64 + d];
        sS[h * 16 + g] = s * 0.125f;
    }
    __syncthreads();
    if (t < 16) {
        float mx = -1e30f;
        for (int g = 0; g < 16; ++g) mx = fmaxf(mx, sS[t * 16 + g]);
        float sum = 0.0f;
        for (int g = 0; g < 16; ++g) {
            float e = expf(sS[t * 16 + g] - mx);
            sS[t * 16 + g] = e;
            sum += e;
        }
        float inv = 1.0f / sum;
        for (int g = 0; g < 16; ++g) sS[t * 16 + g] *= inv;
    }
    __syncthreads();
    #pragma unroll
    for (int j = 0; j < 4; ++j) {
        int o = t + 256 * j;
        int h = o >> 6, d = o & 63;
        float s = 0.0f;
        #pragma unroll
        for (int g = 0; g < 16; ++g) s += sS[h * 16 + g] * sV[g * 64 + d];
        out[(size_t)tok * 1024 + o] = f2bf(s);
    }
}

// ---------------------------------------------------------------------------
// bf16 GEMM:  C[M,N] = A[M,K] . W[N,K]^T  (+ bias, + epilogue)
//   EPI 0: bf16 = acc+bias      EPI 1: f32 = acc+bias+resid (may alias Cout)
//   EPI 2: bf16 = gelu(acc+bias)
// 128x128 tile, BK=32, 4 waves (2x2), each wave 64x64 via 4x4
// mfma_f32_16x16x32_bf16.  Staging via global_load_lds (16 B/lane DMA).
// LDS layout: row-major 128x32, 64 B/row = 4 chunks of 16 B; chunk at
// position cpos holds global chunk cpos ^ ((row>>1)&3)  (bank de-phasing).
// Grid is 1-D; bid&7 = XCD slice over N-tiles (W slice resident in L2),
// N-fastest within slice so A-tiles sweep in lockstep across XCDs (L3 hits).
// Requires: M%128==0, N%1024==0, K%32==0.
// ---------------------------------------------------------------------------
#define BM 128
#define BN 128
#define BK 32

template <int EPI>
__global__ __launch_bounds__(256) void gemm_bf16(
    const unsigned short* __restrict__ A, const unsigned short* __restrict__ W,
    const float* __restrict__ bias, const float* resid, void* Cout,
    int M, int N, int K) {
    __shared__ __align__(16) unsigned short As[BM * BK];   // 8 KB
    __shared__ __align__(16) unsigned short Bs[BN * BK];   // 8 KB

    const int t    = threadIdx.x;
    const int lane = t & 63;
    const int wave = t >> 6;
    const int wm   = wave >> 1;
    const int wn   = wave & 1;

    // ---- XCD-sliced tile mapping ----
    const int nx  = N >> 7;          // N-tiles (divisible by 8)
    const int nx8 = nx >> 3;         // tiles per XCD slice
    const int bid = blockIdx.x;
    const int xcd = bid & 7;
    const int lid = bid >> 3;
    const int mloc = lid / nx8;
    const int nloc = lid - mloc * nx8;
    const int m0 = mloc << 7;
    const int n0 = (xcd * nx8 + nloc) << 7;

    // ---- staging addresses (2 DMA instrs per wave per tile, A and B) ----
    // chunk id ci = wave*64+lane (+256): row = ci>>2, cpos = ci&3,
    // global chunk c = cpos ^ ((row>>1)&3)
    const int rS0   = wave * 16 + (lane >> 2);
    const int rS1   = rS0 + 64;
    const int cpos  = lane & 3;
    const int cg    = cpos ^ ((rS0 >> 1) & 3);   // same for rS1 (row+64)
    const unsigned short* gA0 = A + (size_t)(m0 + rS0) * K + cg * 8;
    const unsigned short* gA1 = A + (size_t)(m0 + rS1) * K + cg * 8;
    const unsigned short* gB0 = W + (size_t)(n0 + rS0) * K + cg * 8;
    const unsigned short* gB1 = W + (size_t)(n0 + rS1) * K + cg * 8;
    unsigned short* lA0 = As + wave * 512;          // HW adds lane*16 B
    unsigned short* lA1 = As + 2048 + wave * 512;
    unsigned short* lB0 = Bs + wave * 512;
    unsigned short* lB1 = Bs + 2048 + wave * 512;

    // ---- fragment read offsets ----
    const int fr  = lane & 15;            // m/n within 16
    const int fq  = lane >> 4;            // k quad -> 8 elements
    const int csw = fq ^ ((fr >> 1) & 3); // de-swizzle chunk position

    f32x4 acc[4][4] = {};

    for (int k0 = 0; k0 < K; k0 += BK) {
        __syncthreads();                   // prior iter's LDS reads done
        g2l16(gA0 + k0, lA0);
        g2l16(gA1 + k0, lA1);
        g2l16(gB0 + k0, lB0);
        g2l16(gB1 + k0, lB1);
        __syncthreads();                   // drains vmcnt: tiles resident

        bf16x8 af[4], bf[4];
        #pragma unroll
        for (int i = 0; i < 4; ++i)
            af[i] = *(const bf16x8*)(As + (wm * 64 + i * 16 + fr) * 32 + csw * 8);
        #pragma unroll
        for (int i = 0; i < 4; ++i)
            bf[i] = *(const bf16x8*)(Bs + (wn * 64 + i * 16 + fr) * 32 + csw * 8);
        #pragma unroll
        for (int im = 0; im < 4; ++im)
            #pragma unroll
            for (int in = 0; in < 4; ++in)
                acc[im][in] = __builtin_amdgcn_mfma_f32_16x16x32_bf16(
                    af[im], bf[in], acc[im][in], 0, 0, 0);
    }

    // epilogue: C/D layout col = lane&15, row = (lane>>4)*4 + e
    #pragma unroll
    for (int in = 0; in < 4; ++in) {
        int col = n0 + wn * 64 + in * 16 + fr;
        float bv = bias[col];
        #pragma unroll
        for (int im = 0; im < 4; ++im) {
            int rowb = m0 + wm * 64 + im * 16 + fq * 4;
            #pragma unroll
            for (int e = 0; e < 4; ++e) {
                size_t idx = (size_t)(rowb + e) * N + col;
                float v = acc[im][in][e] + bv;
                if (EPI == 0) {
                    ((unsigned short*)Cout)[idx] = f2bf(v);
                } else if (EPI == 1) {
                    ((float*)Cout)[idx] = v + resid[idx];
                } else {
                    float g = 0.5f * v * (1.0f + erff(v * 0.70710678118654752f));
                    ((unsigned short*)Cout)[idx] = f2bf(g);
                }
            }
        }
    }
}

// ---------------------------------------------------------------------------
// launch — chunked over token blocks sized to fit ws_size.
// ---------------------------------------------------------------------------
extern "C" void kernel_launch(void* const* d_in, const int* in_sizes, int n_in,
                              void* d_out, int out_size, void* d_ws, size_t ws_size,
                              hipStream_t stream) {
    const float* x      = (const float*)d_in[0];
    const float* qkv_w  = (const float*)d_in[1];
    const float* qkv_b  = (const float*)d_in[2];
    const float* proj_w = (const float*)d_in[3];
    const float* proj_b = (const float*)d_in[4];
    const float* ln1_w  = (const float*)d_in[5];
    const float* ln1_b  = (const float*)d_in[6];
    const float* ln2_w  = (const float*)d_in[7];
    const float* ln2_b  = (const float*)d_in[8];
    const float* mlp_w1 = (const float*)d_in[9];
    const float* mlp_b1 = (const float*)d_in[10];
    const float* mlp_w2 = (const float*)d_in[11];
    const float* mlp_b2 = (const float*)d_in[12];
    float* out = (float*)d_out;

    // persistent bf16 weights: 24 MB
    const size_t WB = 25165824;
    char* ws = (char*)d_ws;
    unsigned short* w_qkv  = (unsigned short*)(ws);              // [3072,1024]
    unsigned short* w_proj = (unsigned short*)(ws + 6291456);    // [1024,1024]
    unsigned short* w_m1   = (unsigned short*)(ws + 8388608);    // [4096,1024]
    unsigned short* w_m2   = (unsigned short*)(ws + 16777216);   // [1024,4096]

    // largest chunk T fitting:  WB + T*(2048 h + 2048 attn + 8192 qkv|m)
    int T = NTOK;
    while (T >= 256 && WB + (size_t)T * 12288 > ws_size) T >>= 1;
    if (T < 256) {
        hipMemcpyAsync(out, x, (size_t)NTOK * DMODEL * sizeof(float),
                       hipMemcpyDeviceToDevice, stream);
        return;
    }

    unsigned short* hbuf = (unsigned short*)(ws + WB);                     // T*2048 B
    unsigned short* abuf = (unsigned short*)(ws + WB + (size_t)T * 2048);  // T*2048 B
    unsigned short* qmbuf= (unsigned short*)(ws + WB + (size_t)T * 4096);  // T*8192 B

    cast_f32_bf16<<<3072, 256, 0, stream>>>((const float4*)qkv_w,  (ushort4*)w_qkv,  786432);
    cast_f32_bf16<<<1024, 256, 0, stream>>>((const float4*)proj_w, (ushort4*)w_proj, 262144);
    cast_f32_bf16<<<4096, 256, 0, stream>>>((const float4*)mlp_w1, (ushort4*)w_m1,   1048576);
    cast_f32_bf16<<<4096, 256, 0, stream>>>((const float4*)mlp_w2, (ushort4*)w_m2,   1048576);

    for (int tok0 = 0; tok0 < NTOK; tok0 += T) {
        const float* xc   = x   + (size_t)tok0 * DMODEL;
        float*       outc = out + (size_t)tok0 * DMODEL;
        const int my = T / BM;

        ln_cast<<<T, 256, 0, stream>>>(xc, ln1_w, ln1_b, hbuf);
        gemm_bf16<0><<<(3072 / BN) * my, 256, 0, stream>>>(
            hbuf, w_qkv, qkv_b, nullptr, qmbuf, T, 3072, 1024);
        attn_heads<<<T, 256, 0, stream>>>(qmbuf, abuf);
        gemm_bf16<1><<<(1024 / BN) * my, 256, 0, stream>>>(
            abuf, w_proj, proj_b, xc, (void*)outc, T, 1024, 1024);
        ln_cast<<<T, 256, 0, stream>>>(outc, ln2_w, ln2_b, hbuf);
        gemm_bf16<2><<<(4096 / BN) * my, 256, 0, stream>>>(
            hbuf, w_m1, mlp_b1, nullptr, qmbuf, T, 4096, 1024);
        gemm_bf16<1><<<(1024 / BN) * my, 256, 0, stream>>>(
            qmbuf, w_m2, mlp_b2, outc, (void*)outc, T, 1024, 4096);
    }
}

// Round 4
// 1018.595 us; speedup vs baseline: 1.0513x; 1.0304x over previous
//
#include <hip/hip_runtime.h>
#include <cstdint>
#include <cmath>

// ---------------------------------------------------------------------------
// SimpleTransformerBlock on MI355X (gfx950)
// B=4, L=4096 -> 16384 tokens, D=1024, HEADS=16, HEAD_DIM=64
// Round 4: XCD-M-sliced tile mapping (A fetched once per XCD, W panels
// L2-resident), BK=64 as two proven BK=32 LDS panels (half the barrier
// drains), fast tanh-GELU epilogue.
// ---------------------------------------------------------------------------

#define NTOK   16384
#define DMODEL 1024

typedef __bf16 bf16x8 __attribute__((ext_vector_type(8)));
typedef float  f32x4  __attribute__((ext_vector_type(4)));
typedef unsigned int __attribute__((address_space(1))) as1_uint;
typedef unsigned int __attribute__((address_space(3))) as3_uint;

__device__ __forceinline__ unsigned short f2bf(float f) {
    unsigned int u = __builtin_bit_cast(unsigned int, f);
    u += 0x7fffu + ((u >> 16) & 1u);          // round-to-nearest-even
    return (unsigned short)(u >> 16);
}
__device__ __forceinline__ float bf2f(unsigned short s) {
    unsigned int u = ((unsigned int)s) << 16;
    return __builtin_bit_cast(float, u);
}

// async global->LDS, 16 B per lane; LDS base wave-uniform (HW adds lane*16)
__device__ __forceinline__ void g2l16(const unsigned short* g, unsigned short* l) {
    __builtin_amdgcn_global_load_lds((const as1_uint*)g, (as3_uint*)l, 16, 0, 0);
}

// ---------------------------------------------------------------------------
// fp32 -> bf16 cast (weights)
// ---------------------------------------------------------------------------
__global__ __launch_bounds__(256) void cast_f32_bf16(
    const float4* __restrict__ in, ushort4* __restrict__ out, int n4) {
    int i = blockIdx.x * 256 + threadIdx.x;
    if (i < n4) {
        float4 v = in[i];
        ushort4 o;
        o.x = f2bf(v.x); o.y = f2bf(v.y); o.z = f2bf(v.z); o.w = f2bf(v.w);
        out[i] = o;
    }
}

// ---------------------------------------------------------------------------
// LayerNorm (fp32 in) -> bf16 out.  One block (256 thr) per token, D=1024.
// ---------------------------------------------------------------------------
__global__ __launch_bounds__(256) void ln_cast(
    const float* __restrict__ x, const float* __restrict__ w,
    const float* __restrict__ b, unsigned short* __restrict__ out) {
    int tok = blockIdx.x;
    int t   = threadIdx.x;
    float4 v = ((const float4*)x)[tok * 256 + t];
    float s  = v.x + v.y + v.z + v.w;
    float ss = v.x * v.x + v.y * v.y + v.z * v.z + v.w * v.w;
    #pragma unroll
    for (int off = 32; off > 0; off >>= 1) {
        s  += __shfl_down(s, off);
        ss += __shfl_down(ss, off);
    }
    __shared__ float red[8];
    int wave = t >> 6;
    if ((t & 63) == 0) { red[wave * 2] = s; red[wave * 2 + 1] = ss; }
    __syncthreads();
    s  = red[0] + red[2] + red[4] + red[6];
    ss = red[1] + red[3] + red[5] + red[7];
    float mu  = s * (1.0f / 1024.0f);
    float var = ss * (1.0f / 1024.0f) - mu * mu;
    float rs  = rsqrtf(var + 1e-5f);
    float4 wv = ((const float4*)w)[t];
    float4 bv = ((const float4*)b)[t];
    ushort4 o;
    o.x = f2bf((v.x - mu) * rs * wv.x + bv.x);
    o.y = f2bf((v.y - mu) * rs * wv.y + bv.y);
    o.z = f2bf((v.z - mu) * rs * wv.z + bv.z);
    o.w = f2bf((v.w - mu) * rs * wv.w + bv.w);
    ((ushort4*)out)[tok * 256 + t] = o;
}

// ---------------------------------------------------------------------------
// Per-token head-attention: qkv row [3][16][64] bf16 -> out row [16*64] bf16.
// ---------------------------------------------------------------------------
__global__ __launch_bounds__(256) void attn_heads(
    const unsigned short* __restrict__ qkv, unsigned short* __restrict__ out) {
    __shared__ float sQ[1024], sK[1024], sV[1024];
    __shared__ float sS[256];
    int tok = blockIdx.x;
    int t   = threadIdx.x;
    const unsigned short* base = qkv + (size_t)tok * 3072;
    for (int i = t; i < 1024; i += 256) {
        sQ[i] = bf2f(base[i]);
        sK[i] = bf2f(base[1024 + i]);
        sV[i] = bf2f(base[2048 + i]);
    }
    __syncthreads();
    {
        int h = t >> 4, g = t & 15;
        float s = 0.0f;
        #pragma unroll
        for (int d = 0; d < 64; ++d) s += sQ[h * 64 + d] * sK[g * 64 + d];
        sS[h * 16 + g] = s * 0.125f;
    }
    __syncthreads();
    if (t < 16) {
        float mx = -1e30f;
        for (int g = 0; g < 16; ++g) mx = fmaxf(mx, sS[t * 16 + g]);
        float sum = 0.0f;
        for (int g = 0; g < 16; ++g) {
            float e = expf(sS[t * 16 + g] - mx);
            sS[t * 16 + g] = e;
            sum += e;
        }
        float inv = 1.0f / sum;
        for (int g = 0; g < 16; ++g) sS[t * 16 + g] *= inv;
    }
    __syncthreads();
    #pragma unroll
    for (int j = 0; j < 4; ++j) {
        int o = t + 256 * j;
        int h = o >> 6, d = o & 63;
        float s = 0.0f;
        #pragma unroll
        for (int g = 0; g < 16; ++g) s += sS[h * 16 + g] * sV[g * 64 + d];
        out[(size_t)tok * 1024 + o] = f2bf(s);
    }
}

// ---------------------------------------------------------------------------
// bf16 GEMM:  C[M,N] = A[M,K] . W[N,K]^T  (+ bias, + epilogue)
//   EPI 0: bf16 = acc+bias   EPI 1: f32 = acc+bias+resid (may alias Cout)
//   EPI 2: bf16 = gelu_tanh(acc+bias)
// 128x128 tile, BK=64 staged as TWO BK=32 panels (each byte-identical to the
// round-3 proven conflict-free layout: row-major 128x32, chunk at pos
// c ^ ((row>>1)&3)).  4 waves (2x2), wave 64x64, 4x4 mfma 16x16x32.
// 32 MFMA per barrier-drain (was 16).  LDS 32 KB.
// Mapping: bid&7 = XCD owns contiguous M/8 slice (A read once per XCD);
// within slice, serpentine over n-panels of 8 tiles (W panel ~2MB hot in L2).
// Requires M%128==0, N%1024==0, K%64==0.
// ---------------------------------------------------------------------------
#define BM 128
#define BN 128

template <int EPI>
__global__ __launch_bounds__(256) void gemm_bf16(
    const unsigned short* __restrict__ A, const unsigned short* __restrict__ W,
    const float* __restrict__ bias, const float* resid, void* Cout,
    int M, int N, int K) {
    __shared__ __align__(16) unsigned short As[2 * 128 * 32];   // 16 KB
    __shared__ __align__(16) unsigned short Bs[2 * 128 * 32];   // 16 KB

    const int t    = threadIdx.x;
    const int lane = t & 63;
    const int wave = t >> 6;
    const int wm   = wave >> 1;
    const int wn   = wave & 1;

    // ---- tile mapping: XCD M-slice + 8-wide n-panels ----
    const int gm = M >> 7, gn = N >> 7;
    int m0, n0;
    if ((gm & 7) == 0) {
        const int xcd = blockIdx.x & 7;
        const int lid = blockIdx.x >> 3;
        const int mX  = gm >> 3;                 // m-tiles per XCD
        const int nsub   = lid & 7;
        const int t2     = lid >> 3;
        const int mloc   = t2 % mX;
        const int npanel = t2 / mX;
        m0 = (xcd * mX + mloc) << 7;
        n0 = (npanel * 8 + nsub) << 7;
    } else {
        m0 = (blockIdx.x / gn) << 7;
        n0 = (blockIdx.x % gn) << 7;
    }

    // ---- staging: per wave, rows [wave*32, wave*32+32), 2 instrs per panel
    // slot s=g*64+lane in panel: row = g*16 + (lane>>2), pos = lane&3,
    // global chunk cg = pos ^ ((row>>1)&3) = (lane&3) ^ ((lane>>3)&3)
    const int rw = wave * 32 + (lane >> 2);
    const int cg = (lane & 3) ^ ((lane >> 3) & 3);
    const unsigned short* gA0 = A + (size_t)(m0 + rw) * K + cg * 8;
    const unsigned short* gA1 = gA0 + (size_t)16 * K;
    const unsigned short* gB0 = W + (size_t)(n0 + rw) * K + cg * 8;
    const unsigned short* gB1 = gB0 + (size_t)16 * K;
    unsigned short* lA0 = As + (wave * 2 + 0) * 512;   // panel 0
    unsigned short* lA1 = As + (wave * 2 + 1) * 512;
    unsigned short* lB0 = Bs + (wave * 2 + 0) * 512;
    unsigned short* lB1 = Bs + (wave * 2 + 1) * 512;

    // ---- fragment read offsets (round-3 proven swizzle, per panel) ----
    const int fr  = lane & 15;
    const int fq  = lane >> 4;
    const int csw = fq ^ ((fr >> 1) & 3);

    f32x4 acc[4][4] = {};

    for (int k0 = 0; k0 < K; k0 += 64) {
        __syncthreads();                    // prior iter's LDS reads done
        g2l16(gA0 + k0,      lA0);          // panel 0 (k0..k0+31)
        g2l16(gA1 + k0,      lA1);
        g2l16(gB0 + k0,      lB0);
        g2l16(gB1 + k0,      lB1);
        g2l16(gA0 + k0 + 32, lA0 + 4096);   // panel 1 (k0+32..k0+63)
        g2l16(gA1 + k0 + 32, lA1 + 4096);
        g2l16(gB0 + k0 + 32, lB0 + 4096);
        g2l16(gB1 + k0 + 32, lB1 + 4096);
        __syncthreads();                    // drains vmcnt: both panels live

        #pragma unroll
        for (int kk = 0; kk < 2; ++kk) {
            bf16x8 af[4], bf[4];
            #pragma unroll
            for (int i = 0; i < 4; ++i)
                af[i] = *(const bf16x8*)(As + kk * 4096 +
                                         (wm * 64 + i * 16 + fr) * 32 + csw * 8);
            #pragma unroll
            for (int i = 0; i < 4; ++i)
                bf[i] = *(const bf16x8*)(Bs + kk * 4096 +
                                         (wn * 64 + i * 16 + fr) * 32 + csw * 8);
            #pragma unroll
            for (int im = 0; im < 4; ++im)
                #pragma unroll
                for (int in = 0; in < 4; ++in)
                    acc[im][in] = __builtin_amdgcn_mfma_f32_16x16x32_bf16(
                        af[im], bf[in], acc[im][in], 0, 0, 0);
        }
    }

    // epilogue: C/D layout col = lane&15, row = (lane>>4)*4 + e
    #pragma unroll
    for (int in = 0; in < 4; ++in) {
        int col = n0 + wn * 64 + in * 16 + fr;
        float bv = bias[col];
        #pragma unroll
        for (int im = 0; im < 4; ++im) {
            int rowb = m0 + wm * 64 + im * 16 + fq * 4;
            #pragma unroll
            for (int e = 0; e < 4; ++e) {
                size_t idx = (size_t)(rowb + e) * N + col;
                float v = acc[im][in][e] + bv;
                if (EPI == 0) {
                    ((unsigned short*)Cout)[idx] = f2bf(v);
                } else if (EPI == 1) {
                    ((float*)Cout)[idx] = v + resid[idx];
                } else {
                    // tanh-form GELU: |err| < ~1e-3, far below bf16 noise
                    float s  = 0.7978845608f * (v + 0.044715f * v * v * v);
                    float e2 = __expf(2.0f * s);
                    float th = 1.0f - 2.0f / (e2 + 1.0f);
                    ((unsigned short*)Cout)[idx] = f2bf(0.5f * v * (1.0f + th));
                }
            }
        }
    }
}

// ---------------------------------------------------------------------------
// launch — chunked over token blocks sized to fit ws_size.
// ---------------------------------------------------------------------------
extern "C" void kernel_launch(void* const* d_in, const int* in_sizes, int n_in,
                              void* d_out, int out_size, void* d_ws, size_t ws_size,
                              hipStream_t stream) {
    const float* x      = (const float*)d_in[0];
    const float* qkv_w  = (const float*)d_in[1];
    const float* qkv_b  = (const float*)d_in[2];
    const float* proj_w = (const float*)d_in[3];
    const float* proj_b = (const float*)d_in[4];
    const float* ln1_w  = (const float*)d_in[5];
    const float* ln1_b  = (const float*)d_in[6];
    const float* ln2_w  = (const float*)d_in[7];
    const float* ln2_b  = (const float*)d_in[8];
    const float* mlp_w1 = (const float*)d_in[9];
    const float* mlp_b1 = (const float*)d_in[10];
    const float* mlp_w2 = (const float*)d_in[11];
    const float* mlp_b2 = (const float*)d_in[12];
    float* out = (float*)d_out;

    // persistent bf16 weights: 24 MB
    const size_t WB = 25165824;
    char* ws = (char*)d_ws;
    unsigned short* w_qkv  = (unsigned short*)(ws);              // [3072,1024]
    unsigned short* w_proj = (unsigned short*)(ws + 6291456);    // [1024,1024]
    unsigned short* w_m1   = (unsigned short*)(ws + 8388608);    // [4096,1024]
    unsigned short* w_m2   = (unsigned short*)(ws + 16777216);   // [1024,4096]

    // largest chunk T fitting:  WB + T*(2048 h + 2048 attn + 8192 qkv|m)
    int T = NTOK;
    while (T >= 256 && WB + (size_t)T * 12288 > ws_size) T >>= 1;
    if (T < 256) {
        hipMemcpyAsync(out, x, (size_t)NTOK * DMODEL * sizeof(float),
                       hipMemcpyDeviceToDevice, stream);
        return;
    }

    unsigned short* hbuf = (unsigned short*)(ws + WB);                     // T*2048 B
    unsigned short* abuf = (unsigned short*)(ws + WB + (size_t)T * 2048);  // T*2048 B
    unsigned short* qmbuf= (unsigned short*)(ws + WB + (size_t)T * 4096);  // T*8192 B

    cast_f32_bf16<<<3072, 256, 0, stream>>>((const float4*)qkv_w,  (ushort4*)w_qkv,  786432);
    cast_f32_bf16<<<1024, 256, 0, stream>>>((const float4*)proj_w, (ushort4*)w_proj, 262144);
    cast_f32_bf16<<<4096, 256, 0, stream>>>((const float4*)mlp_w1, (ushort4*)w_m1,   1048576);
    cast_f32_bf16<<<4096, 256, 0, stream>>>((const float4*)mlp_w2, (ushort4*)w_m2,   1048576);

    for (int tok0 = 0; tok0 < NTOK; tok0 += T) {
        const float* xc   = x   + (size_t)tok0 * DMODEL;
        float*       outc = out + (size_t)tok0 * DMODEL;
        const int my = T / BM;

        ln_cast<<<T, 256, 0, stream>>>(xc, ln1_w, ln1_b, hbuf);
        gemm_bf16<0><<<(3072 / BN) * my, 256, 0, stream>>>(
            hbuf, w_qkv, qkv_b, nullptr, qmbuf, T, 3072, 1024);
        attn_heads<<<T, 256, 0, stream>>>(qmbuf, abuf);
        gemm_bf16<1><<<(1024 / BN) * my, 256, 0, stream>>>(
            abuf, w_proj, proj_b, xc, (void*)outc, T, 1024, 1024);
        ln_cast<<<T, 256, 0, stream>>>(outc, ln2_w, ln2_b, hbuf);
        gemm_bf16<2><<<(4096 / BN) * my, 256, 0, stream>>>(
            hbuf, w_m1, mlp_b1, nullptr, qmbuf, T, 4096, 1024);
        gemm_bf16<1><<<(1024 / BN) * my, 256, 0, stream>>>(
            qmbuf, w_m2, mlp_b2, outc, (void*)outc, T, 1024, 4096);
    }
}